// Round 3
// baseline (387.028 us; speedup 1.0000x reference)
//
#include <hip/hip_runtime.h>

#define N_NODES_C   524288
#define N_EDGES_C   786432
#define NUM_GRAPHS_C 8192
#define NT 16          // NUM_NODE_TYPES
#define NODE_DIM_C 256
#define EDGE_DIM_C 128
#define HDIM 384       // NODE_DIM + EDGE_DIM
#define KC 48          // folded inner dim: 16 (node) + 32 (edge)

// R13: compacted XCD-sliced gather (R12 falsification branch).
// h_node = 32 MiB = 8 x 4 MiB slices = one L2 per XCD (slice = idx>>16).
// Prep counting-sort builds, per (slice, endpoint, graph) bin, the compact
// list of node indices. Edge wave (g,slice) on XCD==slice (blk%8 heuristic,
// correctness-independent) reads ONLY its records; rows are L2-local.
// Node-mean blocks run first and are slice-aligned so their sequential
// stream primes each XCD's L2 for the gather. No em atomics: 8 slice
// partials stored to em8, summed + normalized in k3.
#define NBIN        131072         // 8 slices * 2 endpoints * 8192 graphs
#define FOLD_BLOCKS 72             // ceil(KC*HDIM/256)
#define NODE_BLOCKS 2048           // slice-aligned: r&7 = slice, 4 graphs/blk
#define EDGE_BLOCKS 16384          // wave = (graph, slice); blk%8 = slice
#define NODE_BASE   FOLD_BLOCKS    // 72 % 8 == 0
#define EDGE_BASE   (FOLD_BLOCKS + NODE_BLOCKS)   // 2120 % 8 == 0
#define TOTAL_BLOCKS (FOLD_BLOCKS + NODE_BLOCKS + EDGE_BLOCKS)

// ---------------- workspace layout (bytes, 64-aligned) ----------------
#define WS_NM    0                  // float[8192*16]      512 KB
#define WS_EM8   524288             // float[8][8192][32]  8 MB
#define WS_WC    8912896            // float[48*384]       73728
#define WS_ES    8986624            // int[8193]
#define WS_NS    9019456            // int[8193]
#define WS_CNT   9052288            // int[131072]  counts -> cursors
#define WS_OFFL  9576576            // int[131072]  block-local excl prefix
#define WS_BSUM  10100864           // int[128]
#define WS_BPRE  10101376           // int[128]
#define WS_REC   10101888           // int[1572864] node-index records, 6 MB

__device__ __forceinline__ void f4_add(float4& a, const float4 v) {
    a.x += v.x; a.y += v.y; a.z += v.z; a.w += v.w;
}

__device__ __forceinline__ void f4_shfl_xor_add(float4& a, int mask) {
    a.x += __shfl_xor(a.x, mask, 64);
    a.y += __shfl_xor(a.y, mask, 64);
    a.z += __shfl_xor(a.z, mask, 64);
    a.w += __shfl_xor(a.w, mask, 64);
}

// kZ: zero the bin counters (ws is poisoned between iterations).
__global__ __launch_bounds__(256) void kz_zero(int* __restrict__ cnt) {
    ((int4*)cnt)[blockIdx.x * 256 + threadIdx.x] = make_int4(0, 0, 0, 0);
}

// kA: per-bin counts (bin = (slice*2+endpoint)*8192 + g) + segment bounds.
__global__ __launch_bounds__(256) void ka_count(
    const int* __restrict__ bnode, const int* __restrict__ bedge,
    const int* __restrict__ esrc, const int* __restrict__ edst,
    int* __restrict__ cnt, int* __restrict__ estart, int* __restrict__ nstart) {
    int i = blockIdx.x * 256 + threadIdx.x;
    if (i < N_EDGES_C) {
        int g  = bedge[i];
        int hi = (i + 1 < N_EDGES_C) ? bedge[i + 1] : NUM_GRAPHS_C;
        if (i == 0) for (int q = 0; q <= g; ++q) estart[q] = 0;
        for (int q = g + 1; q <= hi; ++q) estart[q] = i + 1;
        int a = esrc[i], b = edst[i];
        atomicAdd(&cnt[(((a >> 16) * 2 + 0) << 13) + g], 1);
        atomicAdd(&cnt[(((b >> 16) * 2 + 1) << 13) + g], 1);
    }
    if (i < N_NODES_C) {
        int g  = bnode[i];
        int hi = (i + 1 < N_NODES_C) ? bnode[i + 1] : NUM_GRAPHS_C;
        if (i == 0) for (int q = 0; q <= g; ++q) nstart[q] = 0;
        for (int q = g + 1; q <= hi; ++q) nstart[q] = i + 1;
    }
}

// kB: block-local exclusive scan (1024 bins/block) + block sums.
__global__ __launch_bounds__(256) void kb_scan1(
    const int* __restrict__ cnt, int* __restrict__ offl, int* __restrict__ bsum) {
    __shared__ int sh[256];
    int b = blockIdx.x, t = threadIdx.x;
    int4 v = ((const int4*)(cnt + b * 1024))[t];
    int tsum = v.x + v.y + v.z + v.w;
    sh[t] = tsum;
    __syncthreads();
    for (int d = 1; d < 256; d <<= 1) {
        int add = (t >= d) ? sh[t - d] : 0;
        __syncthreads();
        sh[t] += add;
        __syncthreads();
    }
    int base = (t == 0) ? 0 : sh[t - 1];
    int4 o;
    o.x = base; o.y = base + v.x; o.z = base + v.x + v.y; o.w = base + v.x + v.y + v.z;
    ((int4*)(offl + b * 1024))[t] = o;
    if (t == 255) bsum[b] = sh[255];
}

// kC: scan the 128 block sums.
__global__ __launch_bounds__(128) void kc_scan2(
    const int* __restrict__ bsum, int* __restrict__ bpre) {
    __shared__ int sh[128];
    int t = threadIdx.x;
    sh[t] = bsum[t];
    __syncthreads();
    for (int d = 1; d < 128; d <<= 1) {
        int add = (t >= d) ? sh[t - d] : 0;
        __syncthreads();
        sh[t] += add;
        __syncthreads();
    }
    bpre[t] = (t == 0) ? 0 : sh[t - 1];
}

// kS: scatter records; cnt[] reused as down-counting cursor (ends at 0).
__global__ __launch_bounds__(256) void ks_scatter(
    const int* __restrict__ bedge,
    const int* __restrict__ esrc, const int* __restrict__ edst,
    int* __restrict__ cnt, const int* __restrict__ offl,
    const int* __restrict__ bpre, int* __restrict__ rec) {
    int i = blockIdx.x * 256 + threadIdx.x;
    if (i >= N_EDGES_C) return;
    int g = bedge[i];
    int a = esrc[i], b = edst[i];
    int binA = (((a >> 16) * 2 + 0) << 13) + g;
    int binB = (((b >> 16) * 2 + 1) << 13) + g;
    int pA = atomicSub(&cnt[binA], 1) - 1;
    rec[offl[binA] + bpre[binA >> 10] + pA] = a;
    int pB = atomicSub(&cnt[binB], 1) - 1;
    rec[offl[binB] + bpre[binB >> 10] + pB] = b;
}

// KM mega-kernel:
//  blocks [0,72):                 Wc fold (unchanged).
//  blocks [NODE_BASE,+2048):      node means; r&7 = slice octant (g>>10) so the
//     sequential h_node stream primes the owning XCD's L2.
//  blocks [EDGE_BASE,+16384):     edge partials; wave = (g, slice); compacted
//     record list per (slice,p,g); rows L2-local; plain float4 store to em8.
__global__ __launch_bounds__(256) void km_mega(
    const float* __restrict__ h_node,
    const int* __restrict__ estart, const int* __restrict__ nstart,
    const int* __restrict__ offl, const int* __restrict__ bpre,
    const int* __restrict__ rec,
    const float* __restrict__ Wn, const float* __restrict__ We,
    const float* __restrict__ W1,
    float* __restrict__ nm, float* __restrict__ em8, float* __restrict__ Wc) {
    int blk  = blockIdx.x;
    int wave = threadIdx.x >> 6;
    int lane = threadIdx.x & 63;
    const float4* h4 = (const float4*)h_node;
    const float4 z4 = make_float4(0.f, 0.f, 0.f, 0.f);

    if (blk < FOLD_BLOCKS) {
        // ---- weight fold ----
        int o = blk * 256 + threadIdx.x;        // 0..18431 (= KC*HDIM)
        if (o >= KC * HDIM) return;
        int k = o / HDIM, j = o % HDIM;
        float acc = 0.f;
        if (k < NT) {
            const float* wr = &Wn[k * NODE_DIM_C];
            #pragma unroll 16
            for (int kk = 0; kk < NODE_DIM_C; ++kk)
                acc = fmaf(wr[kk], W1[(size_t)kk * HDIM + j], acc);
        } else {
            const float* wr = &We[(k - NT) * EDGE_DIM_C];
            #pragma unroll 16
            for (int kk = 0; kk < EDGE_DIM_C; ++kk)
                acc = fmaf(wr[kk], W1[(size_t)(NODE_DIM_C + kk) * HDIM + j], acc);
        }
        Wc[o] = acc;
    } else if (blk < EDGE_BASE) {
        // ---- node means (slice-aligned placement) ----
        int r = blk - NODE_BASE;
        int s8 = r & 7;                 // target XCD == slice octant
        int g  = s8 * 1024 + (r >> 3) * 4 + wave;
        int s = nstart[g], e = nstart[g + 1];
        int row_off = lane >> 2;   // 0..15
        int quad    = lane & 3;    // 0..3
        float4 a0 = z4, a1 = z4;
        int i = s + row_off;
        for (; i + 16 < e; i += 32) {
            float4 v0 = h4[(size_t)i * 4 + quad];
            float4 v1 = h4[(size_t)(i + 16) * 4 + quad];
            f4_add(a0, v0);
            f4_add(a1, v1);
        }
        if (i < e) f4_add(a0, h4[(size_t)i * 4 + quad]);
        f4_add(a0, a1);
        f4_shfl_xor_add(a0, 4);
        f4_shfl_xor_add(a0, 8);
        f4_shfl_xor_add(a0, 16);
        f4_shfl_xor_add(a0, 32);
        if (row_off == 0) {
            float inv = 1.f / fmaxf((float)(e - s), 1.f);
            ((float4*)nm)[(size_t)g * 4 + quad] =
                make_float4(a0.x * inv, a0.y * inv, a0.z * inv, a0.w * inv);
        }
    } else {
        // ---- edge partial sums (compacted slice-local gather) ----
        int r     = blk - EDGE_BASE;
        int slice = r & 7;                      // == blk%8 == XCD (heuristic)
        int g     = (r >> 3) * 4 + wave;
        int binS  = ((slice * 2 + 0) << 13) + g;
        int binD  = binS + (1 << 13);
        int stS = offl[binS] + bpre[binS >> 10];
        int enS = offl[binS + 1] + bpre[(binS + 1) >> 10];
        int stD = offl[binD] + bpre[binD >> 10];
        int enD = (binD == NBIN - 1) ? 2 * N_EDGES_C
                                     : offl[binD + 1] + bpre[(binD + 1) >> 10];
        int slot = lane >> 3;          // 0..7 record slot
        int p    = (lane >> 2) & 1;    // 0=src 1=dst
        int quad = lane & 3;           // 16 B quarter of the 64-B row
        int st = p ? stD : stS;
        int en = p ? enD : enS;
        int cmax = max(enS - stS, enD - stD);
        int T = (cmax + 7) >> 3;       // wave-uniform trips, 8 recs/list/iter
        float4 acc = z4;
        int i = st + slot;
        int idx = (i < en) ? rec[i] : -1;
        for (int t = 1; t < T; ++t) {
            int i2 = i + 8;
            int nx = (i2 < en) ? rec[i2] : -1;   // prefetch next record
            if (idx >= 0) f4_add(acc, h4[(size_t)idx * 4 + quad]);
            idx = nx; i = i2;
        }
        if (idx >= 0) f4_add(acc, h4[(size_t)idx * 4 + quad]);
        // reduce over slot (lane bits 3..5)
        f4_shfl_xor_add(acc, 8);
        f4_shfl_xor_add(acc, 16);
        f4_shfl_xor_add(acc, 32);
        if (slot == 0) {
            // em8[slice][g] row = 32 floats: quads 0..3 src half, 4..7 dst half
            ((float4*)em8)[((size_t)(slice * NUM_GRAPHS_C + g)) * 8 + p * 4 + quad] = acc;
        }
    }
}

// K3: fused MLP.  f[g] = [nm(g) | (Σ_s em8[s][g]) / ecnt(g)]  (48 dims)
// pred[g] = relu(f[g] @ Wc + b1) . W2 + b2
#define GPB 16
__global__ __launch_bounds__(HDIM) void k3_mlp(
    const float* __restrict__ nm, const float* __restrict__ em8,
    const int* __restrict__ estart,
    const float* __restrict__ Wc, const float* __restrict__ b1,
    const float* __restrict__ W2, const float* __restrict__ b2,
    float* __restrict__ pred) {
    int j = threadIdx.x;
    float wc[KC];
    #pragma unroll
    for (int k = 0; k < KC; ++k) wc[k] = Wc[k * HDIM + j];
    float b1j = b1[j], w2j = W2[j], b20 = b2[0];

    __shared__ float fs[GPB][KC];
    __shared__ float part[GPB][6];
    int g0 = blockIdx.x * GPB;
    for (int t = j; t < GPB * KC; t += HDIM) {
        int g = t / KC, k = t % KC;
        int G = g0 + g;
        float val;
        if (k < NT) {
            val = nm[(size_t)G * NT + k];
        } else {
            float ssum = 0.f;
            #pragma unroll
            for (int s = 0; s < 8; ++s)
                ssum += em8[((size_t)(s * NUM_GRAPHS_C + G)) * 32 + (k - NT)];
            float ec = (float)(estart[G + 1] - estart[G]);
            val = ssum / fmaxf(ec, 1.f);
        }
        fs[g][k] = val;
    }
    __syncthreads();

    int wave = j >> 6, lane = j & 63;
    for (int g = 0; g < GPB; ++g) {
        float z = b1j;
        #pragma unroll
        for (int k = 0; k < KC; ++k) z = fmaf(fs[g][k], wc[k], z);
        z = fmaxf(z, 0.f);
        float p = z * w2j;
        #pragma unroll
        for (int off = 32; off > 0; off >>= 1) p += __shfl_down(p, off, 64);
        if (lane == 0) part[g][wave] = p;
    }
    __syncthreads();
    if (j < GPB) {
        float sacc = b20;
        #pragma unroll
        for (int w = 0; w < 6; ++w) sacc += part[j][w];
        pred[g0 + j] = sacc;
    }
}

extern "C" void kernel_launch(void* const* d_in, const int* in_sizes, int n_in,
                              void* d_out, int out_size, void* d_ws, size_t ws_size,
                              hipStream_t stream) {
    const float* h_node     = (const float*)d_in[0];
    // d_in[1] = pos_node (unused)
    const int*   batch_node = (const int*)d_in[2];
    const int*   edge_index = (const int*)d_in[3];   // [2, E] row-major
    const int*   batch_edge = (const int*)d_in[4];
    const float* W_node     = (const float*)d_in[5];
    const float* W_edge     = (const float*)d_in[6];
    const float* W1         = (const float*)d_in[7];
    const float* b1         = (const float*)d_in[8];
    const float* W2         = (const float*)d_in[9];
    const float* b2         = (const float*)d_in[10];
    float* pred = (float*)d_out;

    char* ws = (char*)d_ws;
    float* nm     = (float*)(ws + WS_NM);
    float* em8    = (float*)(ws + WS_EM8);
    float* Wc     = (float*)(ws + WS_WC);
    int*   estart = (int*)(ws + WS_ES);
    int*   nstart = (int*)(ws + WS_NS);
    int*   cnt    = (int*)(ws + WS_CNT);
    int*   offl   = (int*)(ws + WS_OFFL);
    int*   bsum   = (int*)(ws + WS_BSUM);
    int*   bpre   = (int*)(ws + WS_BPRE);
    int*   rec    = (int*)(ws + WS_REC);

    const int* esrc = edge_index;
    const int* edst = edge_index + N_EDGES_C;

    // counting-sort prep: zero -> count(+bounds) -> scan -> scatter
    kz_zero  <<<128,  256, 0, stream>>>(cnt);
    ka_count <<<3072, 256, 0, stream>>>(batch_node, batch_edge, esrc, edst,
                                        cnt, estart, nstart);
    kb_scan1 <<<128,  256, 0, stream>>>(cnt, offl, bsum);
    kc_scan2 <<<1,    128, 0, stream>>>(bsum, bpre);
    ks_scatter<<<3072,256, 0, stream>>>(batch_edge, esrc, edst, cnt, offl, bpre, rec);
    // KM: fold (72) + slice-aligned node means (2048) + compacted edge gather (16384)
    km_mega  <<<TOTAL_BLOCKS, 256, 0, stream>>>(
        h_node, estart, nstart, offl, bpre, rec, W_node, W_edge, W1, nm, em8, Wc);
    // K3: fold partials + normalize + MLP
    k3_mlp   <<<NUM_GRAPHS_C / GPB, HDIM, 0, stream>>>(
        nm, em8, estart, Wc, b1, W2, b2, pred);
}

// Round 4
// 143.676 us; speedup vs baseline: 2.6937x; 2.6937x over previous
//
#include <hip/hip_runtime.h>

#define N_NODES_C   524288
#define N_EDGES_C   786432
#define NUM_GRAPHS_C 8192
#define NT 16          // NUM_NODE_TYPES
#define NODE_DIM_C 256
#define EDGE_DIM_C 128
#define HDIM 384       // NODE_DIM + EDGE_DIM
#define KC 48          // folded inner dim: 16 (node) + 32 (edge)

// R14: XCD-sliced gather with ATOMIC-FREE compaction (R13 fork 1).
// h_node = 32 MiB = 8 x 4 MiB slices = one L2 per XCD (slice = idx>>16).
// Records for graph g live in the private region [2*estart[g], 2*estart[g+1])
// grouped by bin = slice*2 + endpoint. kr_build: one wave per graph,
// LDS-histogram (16 bins) -> in-wave scan -> LDS-cursor placement. No global
// atomics anywhere. Edge wave (g,slice) on XCD==slice (blk%8 heuristic,
// correctness-independent) reads only its two compact lists; rows L2-local.
// 8 slice partials per graph stored to em8 (no atomics), folded in k3.
#define FOLD_BLOCKS 72             // ceil(KC*HDIM/256)
#define NODE_BLOCKS 2048           // slice-aligned: r&7 = slice octant
#define EDGE_BLOCKS 16384          // wave = (graph, slice); blk%8 = slice
#define NODE_BASE   FOLD_BLOCKS    // 72 % 8 == 0
#define EDGE_BASE   (FOLD_BLOCKS + NODE_BLOCKS)   // 2120 % 8 == 0
#define TOTAL_BLOCKS (FOLD_BLOCKS + NODE_BLOCKS + EDGE_BLOCKS)

// ---------------- workspace layout (bytes, 64-aligned) ----------------
#define WS_NM    0                  // float[8192*16]      512 KB
#define WS_EM8   524288             // float[8][8192][32]  8 MB
#define WS_WC    8912896            // float[48*384]       73728 B
#define WS_ES    8986624            // int[8193]
#define WS_NS    9019456            // int[8193]
#define WS_BOFF  9052288            // int[8192*16] bin start offsets, 512 KB
#define WS_REC   9576576            // int[1572864] node-index records, 6 MB

__device__ __forceinline__ void f4_add(float4& a, const float4 v) {
    a.x += v.x; a.y += v.y; a.z += v.z; a.w += v.w;
}

__device__ __forceinline__ void f4_shfl_xor_add(float4& a, int mask) {
    a.x += __shfl_xor(a.x, mask, 64);
    a.y += __shfl_xor(a.y, mask, 64);
    a.z += __shfl_xor(a.z, mask, 64);
    a.w += __shfl_xor(a.w, mask, 64);
}

// k0: segment starts via boundary detection (batch arrays are sorted).
// estart[g] = first i with bedge[i] >= g; estart[NUM_GRAPHS] = E. Same for nodes.
__global__ __launch_bounds__(256) void k0_prep(
    const int* __restrict__ bnode, const int* __restrict__ bedge,
    int* __restrict__ estart, int* __restrict__ nstart) {
    int i = blockIdx.x * 256 + threadIdx.x;
    if (i < N_EDGES_C) {
        int g0 = bedge[i];
        int hi = (i + 1 < N_EDGES_C) ? bedge[i + 1] : NUM_GRAPHS_C;
        if (i == 0) for (int g = 0; g <= g0; ++g) estart[g] = 0;
        for (int g = g0 + 1; g <= hi; ++g) estart[g] = i + 1;
    }
    if (i < N_NODES_C) {
        int g0 = bnode[i];
        int hi = (i + 1 < N_NODES_C) ? bnode[i + 1] : NUM_GRAPHS_C;
        if (i == 0) for (int g = 0; g <= g0; ++g) nstart[g] = 0;
        for (int g = g0 + 1; g <= hi; ++g) nstart[g] = i + 1;
    }
}

// kr: per-graph record build, one wave per graph, LDS-only atomics.
// Pass 1: histogram the graph's ~96 edges into 16 (slice,endpoint) bins.
// In-wave scan of 16 counts -> absolute bin starts (binoff) + LDS cursors.
// Pass 2: place each endpoint's node index at its bin cursor (6-MB region,
// graph-private, so writes land in a handful of lines; re-reads are L2 hits).
__global__ __launch_bounds__(256) void kr_build(
    const int* __restrict__ esrc, const int* __restrict__ edst,
    const int* __restrict__ estart,
    int* __restrict__ rec, int* __restrict__ binoff) {
    int wave = threadIdx.x >> 6, lane = threadIdx.x & 63;
    int g = blockIdx.x * 4 + wave;
    int s = estart[g], e = estart[g + 1];
    __shared__ int lcnt[4][16];
    __shared__ int lcur[4][16];
    if (lane < 16) lcnt[wave][lane] = 0;      // intra-wave DS ordering suffices
    for (int i = s + lane; i < e; i += 64) {
        int a = esrc[i];
        atomicAdd(&lcnt[wave][((a >> 16) << 1) + 0], 1);
        int b = edst[i];
        atomicAdd(&lcnt[wave][((b >> 16) << 1) + 1], 1);
    }
    int c = (lane < 16) ? lcnt[wave][lane] : 0;
    int incl = c;
    #pragma unroll
    for (int d = 1; d < 16; d <<= 1) {
        int v = __shfl_up(incl, d, 64);
        if (lane >= d) incl += v;
    }
    int excl = incl - c;
    if (lane < 16) {
        lcur[wave][lane] = excl;              // local cursor
        binoff[g * 16 + lane] = 2 * s + excl; // absolute bin start
    }
    for (int i = s + lane; i < e; i += 64) {
        int a = esrc[i];
        int pa = atomicAdd(&lcur[wave][((a >> 16) << 1) + 0], 1);
        rec[2 * s + pa] = a;
        int b = edst[i];
        int pb = atomicAdd(&lcur[wave][((b >> 16) << 1) + 1], 1);
        rec[2 * s + pb] = b;
    }
}

// KM mega-kernel:
//  blocks [0,72):             Wc fold (unchanged).
//  blocks [NODE_BASE,+2048):  node means; r&7 = slice octant (g>>10) so the
//     sequential h_node stream primes the owning XCD's L2.
//  blocks [EDGE_BASE,+16384): edge partials; wave = (g, slice); two compact
//     record lists (src bin 2*slice, dst bin 2*slice+1, adjacent in memory);
//     rows L2-local; plain float4 store to em8.
__global__ __launch_bounds__(256) void km_mega(
    const float* __restrict__ h_node,
    const int* __restrict__ estart, const int* __restrict__ nstart,
    const int* __restrict__ binoff, const int* __restrict__ rec,
    const float* __restrict__ Wn, const float* __restrict__ We,
    const float* __restrict__ W1,
    float* __restrict__ nm, float* __restrict__ em8, float* __restrict__ Wc) {
    int blk  = blockIdx.x;
    int wave = threadIdx.x >> 6;
    int lane = threadIdx.x & 63;
    const float4* h4 = (const float4*)h_node;
    const float4 z4 = make_float4(0.f, 0.f, 0.f, 0.f);

    if (blk < FOLD_BLOCKS) {
        // ---- weight fold ----
        int o = blk * 256 + threadIdx.x;        // 0..18431 (= KC*HDIM)
        if (o >= KC * HDIM) return;
        int k = o / HDIM, j = o % HDIM;
        float acc = 0.f;
        if (k < NT) {
            const float* wr = &Wn[k * NODE_DIM_C];
            #pragma unroll 16
            for (int kk = 0; kk < NODE_DIM_C; ++kk)
                acc = fmaf(wr[kk], W1[(size_t)kk * HDIM + j], acc);
        } else {
            const float* wr = &We[(k - NT) * EDGE_DIM_C];
            #pragma unroll 16
            for (int kk = 0; kk < EDGE_DIM_C; ++kk)
                acc = fmaf(wr[kk], W1[(size_t)(NODE_DIM_C + kk) * HDIM + j], acc);
        }
        Wc[o] = acc;
    } else if (blk < EDGE_BASE) {
        // ---- node means (slice-aligned placement) ----
        int r = blk - NODE_BASE;
        int s8 = r & 7;                 // target XCD == slice octant
        int g  = s8 * 1024 + (r >> 3) * 4 + wave;
        int s = nstart[g], e = nstart[g + 1];
        int row_off = lane >> 2;   // 0..15
        int quad    = lane & 3;    // 0..3
        float4 a0 = z4, a1 = z4;
        int i = s + row_off;
        for (; i + 16 < e; i += 32) {
            float4 v0 = h4[(size_t)i * 4 + quad];
            float4 v1 = h4[(size_t)(i + 16) * 4 + quad];
            f4_add(a0, v0);
            f4_add(a1, v1);
        }
        if (i < e) f4_add(a0, h4[(size_t)i * 4 + quad]);
        f4_add(a0, a1);
        f4_shfl_xor_add(a0, 4);
        f4_shfl_xor_add(a0, 8);
        f4_shfl_xor_add(a0, 16);
        f4_shfl_xor_add(a0, 32);
        if (row_off == 0) {
            float inv = 1.f / fmaxf((float)(e - s), 1.f);
            ((float4*)nm)[(size_t)g * 4 + quad] =
                make_float4(a0.x * inv, a0.y * inv, a0.z * inv, a0.w * inv);
        }
    } else {
        // ---- edge partial sums (compacted slice-local gather) ----
        int r     = blk - EDGE_BASE;
        int slice = r & 7;                      // == blk%8 == XCD (heuristic)
        int g     = (r >> 3) * 4 + wave;
        int base0 = binoff[g * 16 + slice * 2];       // src list start
        int base1 = binoff[g * 16 + slice * 2 + 1];   // dst list start
        int end1  = (slice == 7) ? 2 * estart[g + 1]
                                 : binoff[g * 16 + slice * 2 + 2];
        int slot = lane >> 3;          // 0..7 record slot
        int p    = (lane >> 2) & 1;    // 0=src 1=dst
        int quad = lane & 3;           // 16 B quarter of the 64-B row
        int st = p ? base1 : base0;
        int en = p ? end1  : base1;
        int cmax = max(base1 - base0, end1 - base1);
        int T = (cmax + 7) >> 3;       // wave-uniform trips, 8 recs/list/iter
        float4 acc = z4;
        int i = st + slot;
        int idx = (i < en) ? rec[i] : -1;
        for (int t = 1; t < T; ++t) {
            int i2 = i + 8;
            int nx = (i2 < en) ? rec[i2] : -1;   // prefetch next record
            if (idx >= 0) f4_add(acc, h4[(size_t)idx * 4 + quad]);
            idx = nx; i = i2;
        }
        if (idx >= 0) f4_add(acc, h4[(size_t)idx * 4 + quad]);
        // reduce over slot (lane bits 3..5)
        f4_shfl_xor_add(acc, 8);
        f4_shfl_xor_add(acc, 16);
        f4_shfl_xor_add(acc, 32);
        if (slot == 0) {
            // em8[slice][g] row = 32 floats: quads 0..3 src half, 4..7 dst half
            ((float4*)em8)[((size_t)(slice * NUM_GRAPHS_C + g)) * 8 + p * 4 + quad] = acc;
        }
    }
}

// K3: fused MLP.  f[g] = [nm(g) | (Σ_s em8[s][g]) / ecnt(g)]  (48 dims)
// pred[g] = relu(f[g] @ Wc + b1) . W2 + b2
#define GPB 16
__global__ __launch_bounds__(HDIM) void k3_mlp(
    const float* __restrict__ nm, const float* __restrict__ em8,
    const int* __restrict__ estart,
    const float* __restrict__ Wc, const float* __restrict__ b1,
    const float* __restrict__ W2, const float* __restrict__ b2,
    float* __restrict__ pred) {
    int j = threadIdx.x;
    float wc[KC];
    #pragma unroll
    for (int k = 0; k < KC; ++k) wc[k] = Wc[k * HDIM + j];
    float b1j = b1[j], w2j = W2[j], b20 = b2[0];

    __shared__ float fs[GPB][KC];
    __shared__ float part[GPB][6];
    int g0 = blockIdx.x * GPB;
    for (int t = j; t < GPB * KC; t += HDIM) {
        int g = t / KC, k = t % KC;
        int G = g0 + g;
        float val;
        if (k < NT) {
            val = nm[(size_t)G * NT + k];
        } else {
            float ssum = 0.f;
            #pragma unroll
            for (int s = 0; s < 8; ++s)
                ssum += em8[((size_t)(s * NUM_GRAPHS_C + G)) * 32 + (k - NT)];
            float ec = (float)(estart[G + 1] - estart[G]);
            val = ssum / fmaxf(ec, 1.f);
        }
        fs[g][k] = val;
    }
    __syncthreads();

    int wave = j >> 6, lane = j & 63;
    for (int g = 0; g < GPB; ++g) {
        float z = b1j;
        #pragma unroll
        for (int k = 0; k < KC; ++k) z = fmaf(fs[g][k], wc[k], z);
        z = fmaxf(z, 0.f);
        float p = z * w2j;
        #pragma unroll
        for (int off = 32; off > 0; off >>= 1) p += __shfl_down(p, off, 64);
        if (lane == 0) part[g][wave] = p;
    }
    __syncthreads();
    if (j < GPB) {
        float sacc = b20;
        #pragma unroll
        for (int w = 0; w < 6; ++w) sacc += part[j][w];
        pred[g0 + j] = sacc;
    }
}

extern "C" void kernel_launch(void* const* d_in, const int* in_sizes, int n_in,
                              void* d_out, int out_size, void* d_ws, size_t ws_size,
                              hipStream_t stream) {
    const float* h_node     = (const float*)d_in[0];
    // d_in[1] = pos_node (unused)
    const int*   batch_node = (const int*)d_in[2];
    const int*   edge_index = (const int*)d_in[3];   // [2, E] row-major
    const int*   batch_edge = (const int*)d_in[4];
    const float* W_node     = (const float*)d_in[5];
    const float* W_edge     = (const float*)d_in[6];
    const float* W1         = (const float*)d_in[7];
    const float* b1         = (const float*)d_in[8];
    const float* W2         = (const float*)d_in[9];
    const float* b2         = (const float*)d_in[10];
    float* pred = (float*)d_out;

    char* ws = (char*)d_ws;
    float* nm     = (float*)(ws + WS_NM);
    float* em8    = (float*)(ws + WS_EM8);
    float* Wc     = (float*)(ws + WS_WC);
    int*   estart = (int*)(ws + WS_ES);
    int*   nstart = (int*)(ws + WS_NS);
    int*   binoff = (int*)(ws + WS_BOFF);
    int*   rec    = (int*)(ws + WS_REC);

    const int* esrc = edge_index;
    const int* edst = edge_index + N_EDGES_C;

    // k0: segment bounds (no atomics)
    k0_prep <<<3072, 256, 0, stream>>>(batch_node, batch_edge, estart, nstart);
    // kr: per-graph compaction, wave/graph, LDS-only atomics
    kr_build<<<NUM_GRAPHS_C / 4, 256, 0, stream>>>(esrc, edst, estart, rec, binoff);
    // KM: fold (72) + slice-aligned node means (2048) + compacted edge gather (16384)
    km_mega <<<TOTAL_BLOCKS, 256, 0, stream>>>(
        h_node, estart, nstart, binoff, rec, W_node, W_edge, W1, nm, em8, Wc);
    // K3: fold partials + normalize + MLP
    k3_mlp  <<<NUM_GRAPHS_C / GPB, HDIM, 0, stream>>>(
        nm, em8, estart, Wc, b1, W2, b2, pred);
}